// Round 2
// baseline (645.838 us; speedup 1.0000x reference)
//
#include <hip/hip_runtime.h>
#include <math.h>

// n fixed by problem: angles has n(n-1)/2 = 2016 -> n = 64.
#define N 64
#define NPAIRS (N * (N - 1) / 2)  // 2016

// ---------------------------------------------------------------------------
// Kernel 1: build R^T (rows scaled by mus) from the Givens angle sequence.
// One wave (64 threads). Lane j owns column j of R: col[i] = R[i][j] in VGPRs
// (compile-time indices via full unroll). sincos precomputed in parallel to
// LDS; consumed in 8-wide register-prefetch chunks so the serial FMA chain
// never waits on LDS latency.
// Output layout: RT[k*64 + i] = mus[i] * R[i][k].
// ---------------------------------------------------------------------------
__global__ __launch_bounds__(64) void build_r_kernel(
    const float* __restrict__ angles, const float* __restrict__ mus,
    float* __restrict__ RT) {
  __shared__ float2 cs[NPAIRS];
  const int lane = threadIdx.x;

  for (int k = lane; k < NPAIRS; k += 64) {
    float a = angles[k];
    float s, c;
    sincosf(a, &s, &c);
    cs[k] = make_float2(c, s);
  }
  __syncthreads();

  float col[N];
#pragma unroll
  for (int i = 0; i < N; ++i) col[i] = (i == lane) ? 1.0f : 0.0f;

  int k = 0;
#pragma unroll
  for (int t = 0; t < N - 1; ++t) {
#pragma unroll
    for (int b0 = t + 1; b0 < N; b0 += 8) {
      const int nb = (N - b0) < 8 ? (N - b0) : 8;
      float2 buf[8];
#pragma unroll
      for (int u = 0; u < nb; ++u) buf[u] = cs[k + u];
#pragma unroll
      for (int u = 0; u < nb; ++u) {
        const int b = b0 + u;
        const float rt = col[t];
        const float rb = col[b];
        col[t] = fmaf(buf[u].x, rt, -buf[u].y * rb);
        col[b] = fmaf(buf[u].y, rt, buf[u].x * rb);
      }
      k += nb;
    }
  }

#pragma unroll
  for (int i = 0; i < N; ++i) {
    RT[lane * N + i] = mus[i] * col[i];
  }
}

// ---------------------------------------------------------------------------
// Kernel 2: out[i][j] = sum_k R[i][k] * X[k][j], 2 columns per thread.
// float2 X loads / out stores (8 B/lane, coalesced 512 B/wave).
// RT reads are wave-uniform -> expect scalar s_load; even if they stay
// vector, 16 dwordx4/wave/k hides under 256 FMA-cycles/k.
// acc: 64 x float2 = 128 VGPRs -> ~3 waves/SIMD, plenty of MLP for HBM.
// ---------------------------------------------------------------------------
__global__ __launch_bounds__(256) void apply_r_kernel(
    const float* __restrict__ X, const float* __restrict__ RT,
    float* __restrict__ out, int m) {
  const int m2 = m >> 1;  // m is even (1,000,000)
  const int j2 = blockIdx.x * 256 + threadIdx.x;
  if (j2 >= m2) return;

  float2 acc[N];
#pragma unroll
  for (int i = 0; i < N; ++i) acc[i] = make_float2(0.0f, 0.0f);

  const float2* xp = (const float2*)X + j2;
#pragma unroll 4
  for (int k = 0; k < N; ++k) {
    const float2 x = xp[(size_t)k * m2];
    const float4* r4 = (const float4*)(RT + k * N);
#pragma unroll
    for (int ii = 0; ii < N / 4; ++ii) {
      const float4 r = r4[ii];
      acc[ii * 4 + 0].x = fmaf(r.x, x.x, acc[ii * 4 + 0].x);
      acc[ii * 4 + 0].y = fmaf(r.x, x.y, acc[ii * 4 + 0].y);
      acc[ii * 4 + 1].x = fmaf(r.y, x.x, acc[ii * 4 + 1].x);
      acc[ii * 4 + 1].y = fmaf(r.y, x.y, acc[ii * 4 + 1].y);
      acc[ii * 4 + 2].x = fmaf(r.z, x.x, acc[ii * 4 + 2].x);
      acc[ii * 4 + 2].y = fmaf(r.z, x.y, acc[ii * 4 + 2].y);
      acc[ii * 4 + 3].x = fmaf(r.w, x.x, acc[ii * 4 + 3].x);
      acc[ii * 4 + 3].y = fmaf(r.w, x.y, acc[ii * 4 + 3].y);
    }
  }

  float2* op = (float2*)out + j2;
#pragma unroll
  for (int i = 0; i < N; ++i) {
    op[(size_t)i * m2] = acc[i];
  }
}

extern "C" void kernel_launch(void* const* d_in, const int* in_sizes, int n_in,
                              void* d_out, int out_size, void* d_ws,
                              size_t ws_size, hipStream_t stream) {
  const float* X = (const float*)d_in[0];       // 64 x m fp32
  const float* angles = (const float*)d_in[1];  // 2016 fp32
  const float* mus = (const float*)d_in[2];     // 64 fp32
  float* out = (float*)d_out;                   // 64 x m fp32
  float* RT = (float*)d_ws;                     // 64*64 fp32 scratch (16 KB)

  const int m = in_sizes[0] / N;
  const int m2 = m >> 1;

  build_r_kernel<<<1, 64, 0, stream>>>(angles, mus, RT);

  const int blocks = (m2 + 255) / 256;
  apply_r_kernel<<<blocks, 256, 0, stream>>>(X, RT, out, m);
}